// Round 1
// baseline (902.012 us; speedup 1.0000x reference)
//
#include <hip/hip_runtime.h>

#define TROWS 1048576
#define DIN   64
#define HDIM  128
#define ODIM  32
#define RPB   256                    // rows (=threads) per block
#define NCHUNK (TROWS / RPB)         // 4096 chunks

// ---------------------------------------------------------------------------
// Kernel A: out0 = mask0 ? MLP0(x) : 0 ; per-chunk max of (mask0 ? t : 0)
// ---------------------------------------------------------------------------
__global__ __launch_bounds__(RPB) void expert0_kernel(
    const float* __restrict__ x, const int* __restrict__ topk,
    const float* __restrict__ W0a, const float* __restrict__ b0a,
    const float* __restrict__ W0b, const float* __restrict__ b0b,
    float* __restrict__ out0, int* __restrict__ chunkmax)
{
    const int t = blockIdx.x * RPB + threadIdx.x;

    // load x row (64 floats) into registers
    float xr[DIN];
    {
        const float4* xv = reinterpret_cast<const float4*>(x + (size_t)t * DIN);
        #pragma unroll
        for (int i = 0; i < DIN / 4; ++i) {
            float4 v = xv[i];
            xr[4*i+0] = v.x; xr[4*i+1] = v.y; xr[4*i+2] = v.z; xr[4*i+3] = v.w;
        }
    }
    const int2 tk = reinterpret_cast<const int2*>(topk)[t];
    const bool m0 = (tk.x == 0) || (tk.y == 0);

    float acc[ODIM];
    #pragma unroll
    for (int o = 0; o < ODIM; ++o) acc[o] = b0b[o];

    // MLP0: 64 -> 128 (relu) -> 32, hidden processed in chunks of 8
    #pragma unroll 1
    for (int hc = 0; hc < HDIM; hc += 8) {
        float h[8];
        #pragma unroll
        for (int j = 0; j < 8; ++j) h[j] = b0a[hc + j];
        #pragma unroll
        for (int d = 0; d < DIN; ++d) {
            const float xd = xr[d];
            #pragma unroll
            for (int j = 0; j < 8; ++j)
                h[j] = fmaf(xd, W0a[d * HDIM + hc + j], h[j]);
        }
        #pragma unroll
        for (int j = 0; j < 8; ++j) {
            const float hj = fmaxf(h[j], 0.0f);
            #pragma unroll
            for (int o = 0; o < ODIM; ++o)
                acc[o] = fmaf(hj, W0b[(hc + j) * ODIM + o], acc[o]);
        }
    }

    // masked store of out0
    {
        float4* ov = reinterpret_cast<float4*>(out0 + (size_t)t * ODIM);
        #pragma unroll
        for (int i = 0; i < ODIM / 4; ++i) {
            float4 v;
            v.x = m0 ? acc[4*i+0] : 0.0f;
            v.y = m0 ? acc[4*i+1] : 0.0f;
            v.z = m0 ? acc[4*i+2] : 0.0f;
            v.w = m0 ? acc[4*i+3] : 0.0f;
            ov[i] = v;
        }
    }

    // per-chunk max of (m0 ? t : 0)
    int m = m0 ? t : 0;
    const int lane = threadIdx.x & 63;
    const int wv   = threadIdx.x >> 6;
    #pragma unroll
    for (int off = 32; off > 0; off >>= 1)
        m = max(m, __shfl_down(m, off, 64));
    __shared__ int smax[RPB / 64];
    if (lane == 0) smax[wv] = m;
    __syncthreads();
    if (threadIdx.x == 0) {
        int r = smax[0];
        #pragma unroll
        for (int w2 = 1; w2 < RPB / 64; ++w2) r = max(r, smax[w2]);
        chunkmax[blockIdx.x] = r;
    }
}

// ---------------------------------------------------------------------------
// Kernel B: exclusive prefix-max over the 4096 chunk maxima (single block)
// ---------------------------------------------------------------------------
__global__ __launch_bounds__(1024) void scan_kernel(
    const int* __restrict__ chunkmax, int* __restrict__ excl)
{
    __shared__ int lmax[1024];
    const int tid  = threadIdx.x;          // 1024 threads, 4 chunks each
    const int base = tid * 4;
    int c0 = chunkmax[base + 0];
    int c1 = chunkmax[base + 1];
    int c2 = chunkmax[base + 2];
    int c3 = chunkmax[base + 3];
    lmax[tid] = max(max(c0, c1), max(c2, c3));
    __syncthreads();
    for (int off = 1; off < 1024; off <<= 1) {
        int v = lmax[tid];
        int u = (tid >= off) ? lmax[tid - off] : 0;
        __syncthreads();
        lmax[tid] = max(v, u);
        __syncthreads();
    }
    int run = (tid > 0) ? lmax[tid - 1] : 0;   // exclusive prefix for chunk base
    excl[base + 0] = run; run = max(run, c0);
    excl[base + 1] = run; run = max(run, c1);
    excl[base + 2] = run; run = max(run, c2);
    excl[base + 3] = run;
}

// ---------------------------------------------------------------------------
// Kernel C: idx via local cummax + chunk prefix; filled = out0[idx];
//           out1 = mask1 ? MLP1([x, filled]) : 0 ; out = w*out0 + (1-w)*out1
// ---------------------------------------------------------------------------
__global__ __launch_bounds__(RPB) void expert1_kernel(
    const float* __restrict__ x, const int* __restrict__ topk,
    const float* __restrict__ wts,
    const float* __restrict__ W1a, const float* __restrict__ b1a,
    const float* __restrict__ W1b, const float* __restrict__ b1b,
    const float* __restrict__ out0, const int* __restrict__ excl,
    float* __restrict__ out)
{
    const int t = blockIdx.x * RPB + threadIdx.x;
    const int2 tk = reinterpret_cast<const int2*>(topk)[t];
    const bool m0 = (tk.x == 0) || (tk.y == 0);
    const bool m1 = (tk.x == 1) || (tk.y == 1);

    // block-local inclusive cummax of (m0 ? t : 0), then add chunk prefix
    const int lane = threadIdx.x & 63;
    const int wv   = threadIdx.x >> 6;
    int s = m0 ? t : 0;
    #pragma unroll
    for (int off = 1; off < 64; off <<= 1) {
        int u = __shfl_up(s, off, 64);
        if (lane >= off) s = max(s, u);
    }
    __shared__ int wtot[RPB / 64];
    if (lane == 63) wtot[wv] = s;
    __syncthreads();
    int pre = excl[blockIdx.x];
    #pragma unroll
    for (int w2 = 0; w2 < RPB / 64; ++w2)
        if (w2 < wv) pre = max(pre, wtot[w2]);
    const int idx = max(pre, s);

    // x1 = [x row (64), filled = out0[idx] (32)]
    float xr[DIN + ODIM];
    {
        const float4* xv = reinterpret_cast<const float4*>(x + (size_t)t * DIN);
        #pragma unroll
        for (int i = 0; i < DIN / 4; ++i) {
            float4 v = xv[i];
            xr[4*i+0] = v.x; xr[4*i+1] = v.y; xr[4*i+2] = v.z; xr[4*i+3] = v.w;
        }
        const float4* fv = reinterpret_cast<const float4*>(out0 + (size_t)idx * ODIM);
        #pragma unroll
        for (int i = 0; i < ODIM / 4; ++i) {
            float4 v = fv[i];
            xr[DIN + 4*i+0] = v.x; xr[DIN + 4*i+1] = v.y;
            xr[DIN + 4*i+2] = v.z; xr[DIN + 4*i+3] = v.w;
        }
    }

    float acc[ODIM];
    #pragma unroll
    for (int o = 0; o < ODIM; ++o) acc[o] = b1b[o];

    // MLP1: 96 -> 128 (relu) -> 32
    #pragma unroll 1
    for (int hc = 0; hc < HDIM; hc += 8) {
        float h[8];
        #pragma unroll
        for (int j = 0; j < 8; ++j) h[j] = b1a[hc + j];
        #pragma unroll
        for (int d = 0; d < DIN + ODIM; ++d) {
            const float xd = xr[d];
            #pragma unroll
            for (int j = 0; j < 8; ++j)
                h[j] = fmaf(xd, W1a[d * HDIM + hc + j], h[j]);
        }
        #pragma unroll
        for (int j = 0; j < 8; ++j) {
            const float hj = fmaxf(h[j], 0.0f);
            #pragma unroll
            for (int o = 0; o < ODIM; ++o)
                acc[o] = fmaf(hj, W1b[(hc + j) * ODIM + o], acc[o]);
        }
    }

    // out = w * out0[t] + (1-w) * (m1 ? e1 : 0)
    const float wgt  = reinterpret_cast<const float2*>(wts)[t].x;
    const float wgtc = 1.0f - wgt;
    const float4* own = reinterpret_cast<const float4*>(out0 + (size_t)t * ODIM);
    float4* outv = reinterpret_cast<float4*>(out + (size_t)t * ODIM);
    #pragma unroll
    for (int i = 0; i < ODIM / 4; ++i) {
        float4 a = own[i];
        float4 r;
        r.x = wgt * a.x + wgtc * (m1 ? acc[4*i+0] : 0.0f);
        r.y = wgt * a.y + wgtc * (m1 ? acc[4*i+1] : 0.0f);
        r.z = wgt * a.z + wgtc * (m1 ? acc[4*i+2] : 0.0f);
        r.w = wgt * a.w + wgtc * (m1 ? acc[4*i+3] : 0.0f);
        outv[i] = r;
    }
}

// ---------------------------------------------------------------------------
extern "C" void kernel_launch(void* const* d_in, const int* in_sizes, int n_in,
                              void* d_out, int out_size, void* d_ws, size_t ws_size,
                              hipStream_t stream)
{
    const float* x    = (const float*)d_in[0];
    const int*   topk = (const int*)  d_in[1];
    const float* wts  = (const float*)d_in[2];
    const float* W0a  = (const float*)d_in[3];
    const float* b0a  = (const float*)d_in[4];
    const float* W0b  = (const float*)d_in[5];
    const float* b0b  = (const float*)d_in[6];
    const float* W1a  = (const float*)d_in[7];
    const float* b1a  = (const float*)d_in[8];
    const float* W1b  = (const float*)d_in[9];
    const float* b1b  = (const float*)d_in[10];
    float* out = (float*)d_out;

    // workspace layout: [out0: T*32 f32][chunkmax: 4096 i32][excl: 4096 i32]
    float* out0     = (float*)d_ws;
    int*   chunkmax = (int*)((char*)d_ws + (size_t)TROWS * ODIM * sizeof(float));
    int*   excl     = chunkmax + NCHUNK;

    expert0_kernel<<<dim3(NCHUNK), dim3(RPB), 0, stream>>>(
        x, topk, W0a, b0a, W0b, b0b, out0, chunkmax);
    scan_kernel<<<dim3(1), dim3(1024), 0, stream>>>(chunkmax, excl);
    expert1_kernel<<<dim3(NCHUNK), dim3(RPB), 0, stream>>>(
        x, topk, wts, W1a, b1a, W1b, b1b, out0, excl, out);
}

// Round 2
// 271.954 us; speedup vs baseline: 3.3168x; 3.3168x over previous
//
#include <hip/hip_runtime.h>
#include <hip/hip_bf16.h>

#define TROWS 1048576
#define RPB   256                    // rows per block
#define NCHUNK (TROWS / RPB)         // 4096

typedef float f32x4  __attribute__((ext_vector_type(4)));
typedef short bf16x8 __attribute__((ext_vector_type(8)));

#define MFMA(a, b, c) __builtin_amdgcn_mfma_f32_16x16x32_bf16(a, b, c, 0, 0, 0)

__device__ __forceinline__ short f2bf(float v) {
    __hip_bfloat16 b = __float2bfloat16(v);
    return __builtin_bit_cast(short, b);
}

// k-map used consistently for ALL A/B fragments: kappa(g,j) = j<4 ? 4g+j : 16+4g+(j-4)
// (any bijection works as long as A and B agree — MFMA contracts k positionally)

// ---------------------------------------------------------------------------
// Prep: weights -> bf16 fragment order. frag ids:
//   W0a [K=64 ][N=128]: 0..15  (ks*8+nt)   W0b [K=128][N=32]: 16..23 (ks*2+ot)
//   W1a [K=96 ][N=128]: 24..47 (ks*8+nt)   W1b [K=128][N=32]: 48..55 (ks*2+ot)
// frag element: lane l=16g+c, slot j -> W[32*ks + kappa(g,j)][16*nt + c]
// ---------------------------------------------------------------------------
__global__ __launch_bounds__(64) void prep_kernel(
    const float* __restrict__ W0a, const float* __restrict__ W0b,
    const float* __restrict__ W1a, const float* __restrict__ W1b,
    bf16x8* __restrict__ frag)
{
    const int fid = blockIdx.x, l = threadIdx.x, c = l & 15, g = l >> 4;
    const float* W; int N, ks, nt;
    if (fid < 16)      { W = W0a; N = 128; ks = fid >> 3;        nt = fid & 7; }
    else if (fid < 24) { W = W0b; N = 32;  ks = (fid - 16) >> 1; nt = (fid - 16) & 1; }
    else if (fid < 48) { W = W1a; N = 128; ks = (fid - 24) >> 3; nt = (fid - 24) & 7; }
    else               { W = W1b; N = 32;  ks = (fid - 48) >> 1; nt = (fid - 48) & 1; }
    bf16x8 f;
    #pragma unroll
    for (int j = 0; j < 8; ++j) {
        const int k = 32 * ks + ((j < 4) ? (4 * g + j) : (16 + 4 * g + (j - 4)));
        f[j] = f2bf(W[k * N + 16 * nt + c]);
    }
    frag[fid * 64 + l] = f;
}

// ---------------------------------------------------------------------------
// Kernel A: out0 = mask0 ? MLP0(x) : 0  (MFMA, swapped operands); chunk max
// block = 256 thr = 4 waves; wave handles 64 rows = 4 row-tiles of 16
// ---------------------------------------------------------------------------
__global__ __launch_bounds__(256) void expert0_kernel(
    const float* __restrict__ x, const int* __restrict__ topk,
    const float* __restrict__ b0a, const float* __restrict__ b0b,
    const bf16x8* __restrict__ frag,
    float* __restrict__ out0, int* __restrict__ chunkmax)
{
    const int tid = threadIdx.x, wv = tid >> 6, l = tid & 63, c = l & 15, g = l >> 4;

    bf16x8 wa[2][8], wb[4][2];
    #pragma unroll
    for (int ks = 0; ks < 2; ++ks)
        #pragma unroll
        for (int nt = 0; nt < 8; ++nt) wa[ks][nt] = frag[(ks * 8 + nt) * 64 + l];
    #pragma unroll
    for (int ks = 0; ks < 4; ++ks)
        #pragma unroll
        for (int ot = 0; ot < 2; ++ot) wb[ks][ot] = frag[(16 + ks * 2 + ot) * 64 + l];

    #pragma unroll 1
    for (int rt = 0; rt < 4; ++rt) {
        const int rowbase = blockIdx.x * RPB + wv * 64 + rt * 16;
        const float* xr = x + (size_t)(rowbase + c) * 64;

        bf16x8 xf[2];
        #pragma unroll
        for (int ks = 0; ks < 2; ++ks) {
            f32x4 a = *(const f32x4*)(xr + 32 * ks + 4 * g);
            f32x4 b = *(const f32x4*)(xr + 32 * ks + 16 + 4 * g);
            #pragma unroll
            for (int j = 0; j < 4; ++j) { xf[ks][j] = f2bf(a[j]); xf[ks][4 + j] = f2bf(b[j]); }
        }

        f32x4 acc1[8];
        #pragma unroll
        for (int nt = 0; nt < 8; ++nt) acc1[nt] = *(const f32x4*)(b0a + 16 * nt + 4 * g);
        #pragma unroll
        for (int ks = 0; ks < 2; ++ks)
            #pragma unroll
            for (int nt = 0; nt < 8; ++nt) acc1[nt] = MFMA(wa[ks][nt], xf[ks], acc1[nt]);

        bf16x8 hf[4];               // H[c][32*k2 + kappa(g,j)] = acc1[2*k2+(j>>2)][j&3]
        #pragma unroll
        for (int k2 = 0; k2 < 4; ++k2)
            #pragma unroll
            for (int j = 0; j < 8; ++j)
                hf[k2][j] = f2bf(fmaxf(acc1[2 * k2 + (j >> 2)][j & 3], 0.0f));

        f32x4 acc2[2];
        #pragma unroll
        for (int ot = 0; ot < 2; ++ot) acc2[ot] = *(const f32x4*)(b0b + 16 * ot + 4 * g);
        #pragma unroll
        for (int k2 = 0; k2 < 4; ++k2)
            #pragma unroll
            for (int ot = 0; ot < 2; ++ot) acc2[ot] = MFMA(wb[k2][ot], hf[k2], acc2[ot]);

        const int row = rowbase + c;
        const int2 tk = ((const int2*)topk)[row];
        const bool m0 = (tk.x == 0) || (tk.y == 0);
        #pragma unroll
        for (int ot = 0; ot < 2; ++ot) {
            f32x4 v;
            #pragma unroll
            for (int j = 0; j < 4; ++j) v[j] = m0 ? acc2[ot][j] : 0.0f;
            *(f32x4*)(out0 + (size_t)row * 32 + 16 * ot + 4 * g) = v;
        }
    }

    // per-chunk max of (m0 ? t : 0), own-tid row ordering
    const int t = blockIdx.x * RPB + tid;
    const int2 tko = ((const int2*)topk)[t];
    int m = ((tko.x == 0) || (tko.y == 0)) ? t : 0;
    #pragma unroll
    for (int off = 32; off > 0; off >>= 1) m = max(m, __shfl_down(m, off, 64));
    __shared__ int smax[4];
    if (l == 0) smax[wv] = m;
    __syncthreads();
    if (tid == 0)
        chunkmax[blockIdx.x] = max(max(smax[0], smax[1]), max(smax[2], smax[3]));
}

// ---------------------------------------------------------------------------
// Kernel B: exclusive prefix-max over 4096 chunk maxima (single block)
// ---------------------------------------------------------------------------
__global__ __launch_bounds__(1024) void scan_kernel(
    const int* __restrict__ chunkmax, int* __restrict__ excl)
{
    __shared__ int lmax[1024];
    const int tid = threadIdx.x;
    const int base = tid * 4;
    int c0 = chunkmax[base + 0];
    int c1 = chunkmax[base + 1];
    int c2 = chunkmax[base + 2];
    int c3 = chunkmax[base + 3];
    lmax[tid] = max(max(c0, c1), max(c2, c3));
    __syncthreads();
    for (int off = 1; off < 1024; off <<= 1) {
        int v = lmax[tid];
        int u = (tid >= off) ? lmax[tid - off] : 0;
        __syncthreads();
        lmax[tid] = max(v, u);
        __syncthreads();
    }
    int run = (tid > 0) ? lmax[tid - 1] : 0;
    excl[base + 0] = run; run = max(run, c0);
    excl[base + 1] = run; run = max(run, c1);
    excl[base + 2] = run; run = max(run, c2);
    excl[base + 3] = run;
}

// ---------------------------------------------------------------------------
// Kernel C: idx via cummax; filled = out0[idx]; MLP1 (MFMA swapped); blend
// ---------------------------------------------------------------------------
__global__ __launch_bounds__(256) void expert1_kernel(
    const float* __restrict__ x, const int* __restrict__ topk,
    const float* __restrict__ wts,
    const float* __restrict__ b1a, const float* __restrict__ b1b,
    const bf16x8* __restrict__ frag,
    const float* __restrict__ out0, const int* __restrict__ excl,
    float* __restrict__ out)
{
    const int tid = threadIdx.x, wv = tid >> 6, l = tid & 63, c = l & 15, g = l >> 4;

    bf16x8 wa[3][8], wb[4][2];
    #pragma unroll
    for (int ks = 0; ks < 3; ++ks)
        #pragma unroll
        for (int nt = 0; nt < 8; ++nt) wa[ks][nt] = frag[(24 + ks * 8 + nt) * 64 + l];
    #pragma unroll
    for (int ks = 0; ks < 4; ++ks)
        #pragma unroll
        for (int ot = 0; ot < 2; ++ot) wb[ks][ot] = frag[(48 + ks * 2 + ot) * 64 + l];

    // block-local inclusive cummax of (m0 ? t : 0) + chunk prefix
    const int t = blockIdx.x * RPB + tid;
    const int2 tko = ((const int2*)topk)[t];
    const bool m0o = (tko.x == 0) || (tko.y == 0);
    int s = m0o ? t : 0;
    #pragma unroll
    for (int off = 1; off < 64; off <<= 1) {
        int u = __shfl_up(s, off, 64);
        if (l >= off) s = max(s, u);
    }
    __shared__ int wtot[4];
    if (l == 63) wtot[wv] = s;
    __syncthreads();
    int pre = excl[blockIdx.x];
    #pragma unroll
    for (int w2 = 0; w2 < 4; ++w2)
        if (w2 < wv) pre = max(pre, wtot[w2]);
    const int sidx = max(pre, s);           // idx for row (blockIdx*256 + tid)

    #pragma unroll 1
    for (int rt = 0; rt < 4; ++rt) {
        const int rowbase = blockIdx.x * RPB + wv * 64 + rt * 16;
        const float* xr = x + (size_t)(rowbase + c) * 64;

        bf16x8 xf[3];
        #pragma unroll
        for (int ks = 0; ks < 2; ++ks) {
            f32x4 a = *(const f32x4*)(xr + 32 * ks + 4 * g);
            f32x4 b = *(const f32x4*)(xr + 32 * ks + 16 + 4 * g);
            #pragma unroll
            for (int j = 0; j < 4; ++j) { xf[ks][j] = f2bf(a[j]); xf[ks][4 + j] = f2bf(b[j]); }
        }
        // filled = out0[idx(row)] : idx for row rowbase+c lives at lane rt*16+c
        const int idxc = __shfl(sidx, rt * 16 + c, 64);
        {
            const float* fr = out0 + (size_t)idxc * 32;
            f32x4 a = *(const f32x4*)(fr + 4 * g);
            f32x4 b = *(const f32x4*)(fr + 16 + 4 * g);
            #pragma unroll
            for (int j = 0; j < 4; ++j) { xf[2][j] = f2bf(a[j]); xf[2][4 + j] = f2bf(b[j]); }
        }

        f32x4 acc1[8];
        #pragma unroll
        for (int nt = 0; nt < 8; ++nt) acc1[nt] = *(const f32x4*)(b1a + 16 * nt + 4 * g);
        #pragma unroll
        for (int ks = 0; ks < 3; ++ks)
            #pragma unroll
            for (int nt = 0; nt < 8; ++nt) acc1[nt] = MFMA(wa[ks][nt], xf[ks], acc1[nt]);

        bf16x8 hf[4];
        #pragma unroll
        for (int k2 = 0; k2 < 4; ++k2)
            #pragma unroll
            for (int j = 0; j < 8; ++j)
                hf[k2][j] = f2bf(fmaxf(acc1[2 * k2 + (j >> 2)][j & 3], 0.0f));

        f32x4 acc2[2];
        #pragma unroll
        for (int ot = 0; ot < 2; ++ot) acc2[ot] = *(const f32x4*)(b1b + 16 * ot + 4 * g);
        #pragma unroll
        for (int k2 = 0; k2 < 4; ++k2)
            #pragma unroll
            for (int ot = 0; ot < 2; ++ot) acc2[ot] = MFMA(wb[k2][ot], hf[k2], acc2[ot]);

        // blend: out = w*out0 + (1-w)*(m1 ? e1 : 0)
        const int row = rowbase + c;
        const int2 tk = ((const int2*)topk)[row];
        const bool m1 = (tk.x == 1) || (tk.y == 1);
        const float w = ((const float2*)wts)[row].x;
        const float wc = 1.0f - w;
        #pragma unroll
        for (int ot = 0; ot < 2; ++ot) {
            f32x4 o0 = *(const f32x4*)(out0 + (size_t)row * 32 + 16 * ot + 4 * g);
            f32x4 r;
            #pragma unroll
            for (int j = 0; j < 4; ++j) {
                const float e1 = m1 ? acc2[ot][j] : 0.0f;
                r[j] = w * o0[j] + wc * e1;
            }
            *(f32x4*)(out + (size_t)row * 32 + 16 * ot + 4 * g) = r;
        }
    }
}

// ---------------------------------------------------------------------------
extern "C" void kernel_launch(void* const* d_in, const int* in_sizes, int n_in,
                              void* d_out, int out_size, void* d_ws, size_t ws_size,
                              hipStream_t stream)
{
    const float* x    = (const float*)d_in[0];
    const int*   topk = (const int*)  d_in[1];
    const float* wts  = (const float*)d_in[2];
    const float* W0a  = (const float*)d_in[3];
    const float* b0a  = (const float*)d_in[4];
    const float* W0b  = (const float*)d_in[5];
    const float* b0b  = (const float*)d_in[6];
    const float* W1a  = (const float*)d_in[7];
    const float* b1a  = (const float*)d_in[8];
    const float* W1b  = (const float*)d_in[9];
    const float* b1b  = (const float*)d_in[10];
    float* out = (float*)d_out;

    // ws layout: [frag: 56 KiB][out0: T*32 f32 = 128 MiB][chunkmax][excl]
    bf16x8* frag    = (bf16x8*)d_ws;
    float*  out0    = (float*)((char*)d_ws + 56 * 1024);
    int*    chunkmax= (int*)((char*)out0 + (size_t)TROWS * 32 * sizeof(float));
    int*    excl    = chunkmax + NCHUNK;

    prep_kernel<<<dim3(56), dim3(64), 0, stream>>>(W0a, W0b, W1a, W1b, frag);
    expert0_kernel<<<dim3(NCHUNK), dim3(RPB), 0, stream>>>(
        x, topk, b0a, b0b, frag, out0, chunkmax);
    scan_kernel<<<dim3(1), dim3(1024), 0, stream>>>(chunkmax, excl);
    expert1_kernel<<<dim3(NCHUNK), dim3(RPB), 0, stream>>>(
        x, topk, wts, b1a, b1b, frag, out0, excl, out);
}